// Round 8
// baseline (458.042 us; speedup 1.0000x reference)
//
#include <hip/hip_runtime.h>
#include <hip/hip_bf16.h>
#include <math.h>

typedef short short8 __attribute__((ext_vector_type(8)));
typedef float f32x16 __attribute__((ext_vector_type(16)));

constexpr int D = 768;    // model dim
constexpr int E = 8;      // experts
constexpr int F = 3072;   // ffn dim
constexpr int FH = 1536;  // F half
constexpr int T = 8192;   // tokens
constexpr float EPS = 1e-6f;

static __device__ inline unsigned short f2bf(float f) {
    __hip_bfloat16 h = __float2bfloat16(f);
    return *reinterpret_cast<unsigned short*>(&h);
}

static __device__ inline f32x16 mfma_bf16(short8 a, short8 b, f32x16 c) {
    return __builtin_amdgcn_mfma_f32_32x32x16_bf16(a, b, c, 0, 0, 0);
}

// async global->LDS, 16B per lane; LDS dest = wave-uniform base + lane*16
#define GLL16(g, s) __builtin_amdgcn_global_load_lds( \
    (const __attribute__((address_space(1))) unsigned int*)(g), \
    (__attribute__((address_space(3))) unsigned int*)(s), 16, 0, 0)

// ---------------------------------------------------------------------------
// Weight conversion: wi' = bf16(wi * ln_w) (ln_w folded), wo' = bf16(wo).
// ---------------------------------------------------------------------------
__global__ __launch_bounds__(256)
void convert_weights(const float* __restrict__ wi, const float* __restrict__ wo,
                     const float* __restrict__ lnw,
                     unsigned short* __restrict__ wip, unsigned short* __restrict__ wop)
{
    const unsigned NWI = (unsigned)E * F * D;
    unsigned i4 = (blockIdx.x * 256u + threadIdx.x) * 4u;
    if (i4 < NWI) {
        float4 v = *(const float4*)(wi + i4);
        unsigned e = i4 / (unsigned)(F * D);
        unsigned d = i4 % (unsigned)D;
        float4 l = *(const float4*)(lnw + e * D + d);
        ushort4 o = { f2bf(v.x * l.x), f2bf(v.y * l.y), f2bf(v.z * l.z), f2bf(v.w * l.w) };
        *(ushort4*)(wip + i4) = o;
    } else {
        unsigned j = i4 - NWI;
        float4 v = *(const float4*)(wo + j);
        ushort4 o = { f2bf(v.x), f2bf(v.y), f2bf(v.z), f2bf(v.w) };
        *(ushort4*)(wop + j) = o;
    }
}

// ---------------------------------------------------------------------------
// Router + RMS-norm: logits (exact fp32), top-2, xn = bf16(x*rstd),
// out = wsum*x (residual term), per-token meta (sel, w01). NO atomics.
// ---------------------------------------------------------------------------
__global__ __launch_bounds__(256)
void router_norm_kernel(const float* __restrict__ x,
                        const float* __restrict__ rw,
                        float* __restrict__ logits,        // [T, E]
                        unsigned short* __restrict__ xn,   // [T, D] bf16
                        float* __restrict__ out,           // [T, D] <- wsum*x
                        int*   __restrict__ sel,           // [T] e0 | e1<<4
                        float2* __restrict__ w01)          // [T] (w0, w1)
{
    const int lane = threadIdx.x & 63;
    const int wid  = threadIdx.x >> 6;
    const int t = blockIdx.x * 4 + wid;
    if (t >= T) return;

    const float* xr = x + (size_t)t * D;
    float xv[12];
    float acc[8];
#pragma unroll
    for (int e = 0; e < 8; ++e) acc[e] = 0.f;
    float ssq = 0.f;
#pragma unroll
    for (int i = 0; i < 12; ++i) {
        const int k = lane + 64 * i;
        const float v = xr[k];
        xv[i] = v;
        ssq += v * v;
#pragma unroll
        for (int e = 0; e < 8; ++e) acc[e] += v * rw[e * D + k];
    }
#pragma unroll
    for (int off = 32; off; off >>= 1) {
        ssq += __shfl_xor(ssq, off);
#pragma unroll
        for (int e = 0; e < 8; ++e) acc[e] += __shfl_xor(acc[e], off);
    }

    int e0 = 0; float m0 = acc[0];
#pragma unroll
    for (int e = 1; e < 8; ++e) if (acc[e] > m0) { m0 = acc[e]; e0 = e; }
    int e1 = -1; float m1 = -3.4e38f;
#pragma unroll
    for (int e = 0; e < 8; ++e) if (e != e0 && acc[e] > m1) { m1 = acc[e]; e1 = e; }

    const float r  = expf(m1 - m0);
    const float w0 = 1.f / (1.f + r);
    const float w1 = r * w0;
    const float wsum = w0 + w1;
    const float rs = rsqrtf(ssq * (1.f / (float)D) + EPS);

    if (lane == 0) {
#pragma unroll
        for (int e = 0; e < 8; ++e) logits[t * 8 + e] = acc[e];
        sel[t] = e0 | (e1 << 4);
        w01[t] = make_float2(w0, w1);
    }

#pragma unroll
    for (int i = 0; i < 12; ++i) {
        const int k = lane + 64 * i;
        xn[(size_t)t * D + k] = f2bf(xv[i] * rs);
        out[(size_t)t * D + k] = wsum * xv[i];
    }
}

// ---------------------------------------------------------------------------
// List build: one block per expert, ballot/prefix compaction. Zero atomics.
// ---------------------------------------------------------------------------
__global__ __launch_bounds__(256)
void build_lists(const int* __restrict__ sel, const float2* __restrict__ w01,
                 int* __restrict__ counts, int* __restrict__ lists,
                 float* __restrict__ wlist)
{
    const int e = blockIdx.x;
    const int tid = threadIdx.x;
    const int lane = tid & 63;
    const int wv = tid >> 6;
    __shared__ int wtot[4];
    int cnt = 0;
    for (int c0 = 0; c0 < T; c0 += 256) {
        const int t = c0 + tid;
        const int s = sel[t];
        const bool m1 = ((s >> 4) & 15) == e;
        const bool m = ((s & 15) == e) || m1;
        const unsigned long long b = __ballot(m);
        const int pre = __popcll(b & ((1ULL << lane) - 1ULL));
        if (lane == 0) wtot[wv] = __popcll(b);
        __syncthreads();
        int wbase = 0;
#pragma unroll
        for (int i = 0; i < 4; ++i) if (i < wv) wbase += wtot[i];
        if (m) {
            const int pos = cnt + wbase + pre;
            lists[e * T + pos] = (t << 1) | (m1 ? 1 : 0);
            const float2 w = w01[t];
            wlist[e * T + pos] = m1 ? w.y : w.x;
        }
        cnt += wtot[0] + wtot[1] + wtot[2] + wtot[3];
        __syncthreads();
    }
    if (tid == 0) counts[e] = cnt;
}

// ===========================================================================
// 256x256 8-wave multi-phase GEMM core. BK=64, dbuf 128 KB LDS, 512 thr.
// Wave grid 2M x 4N -> per-wave tile 128x64 (acc 4x2 f32x16 = 128 VGPR).
// Per K-tile: 4 phases {stage quarter of next tile (2 GLL) || ds_read
// quadrant (12 b128) -> lgkmcnt(0)+schedbar -> setprio(1) 8 MFMA setprio(0)},
// then vmcnt(0) (own stages, issued 1-4 phases ago -> nearly landed) +
// s_barrier (publishes ALL waves' stages; vmcnt is per-wave). One barrier
// per K-tile. Rule-21 swizzle: linear LDS dest + inverse-swizzled global
// source + swizzled ds_read.
// ===========================================================================

#define GEMM8W_LOOP(NKT)                                                      \
    _Pragma("unroll")                                                         \
    for (int p = 0; p < 4; ++p) {                                             \
        GLL16(aS[p], smem + p * 8192 + dOff);                                 \
        GLL16(bS[p], smem + 32768 + p * 8192 + dOff);                         \
    }                                                                         \
    asm volatile("s_waitcnt vmcnt(0)" ::: "memory");                          \
    __syncthreads();                                                          \
    int bsel = 0;                                                             \
    for (int kt = 0; kt < (NKT); ++kt) {                                      \
        const char* bufA = smem + bsel * 65536;                               \
        const char* bufB = bufA + 32768;                                      \
        char* nbuf = smem + (bsel ^ 1) * 65536;                               \
        const int kg = (kt + 1) * 64;                                         \
        const bool st = (kt + 1) < (NKT);                                     \
        _Pragma("unroll")                                                     \
        for (int p = 0; p < 4; ++p) {                                         \
            if (st) {                                                         \
                GLL16(aS[p] + kg, nbuf + p * 8192 + dOff);                    \
                GLL16(bS[p] + kg, nbuf + 32768 + p * 8192 + dOff);            \
            }                                                                 \
            short8 fa0[4], fa1[4], fb[4];                                     \
            const int m2 = (p >> 1) * 2, nn = p & 1;                          \
            _Pragma("unroll")                                                 \
            for (int ks = 0; ks < 4; ++ks) {                                  \
                const int co = (hi * 16 + ks * 32) ^ rx;                      \
                const int ar0 = wr * 128 + m2 * 32 + lo;                      \
                fa0[ks] = *(const short8*)(bufA + ar0 * 128 + co);            \
                fa1[ks] = *(const short8*)(bufA + (ar0 + 32) * 128 + co);     \
                const int br = wcn * 64 + nn * 32 + lo;                       \
                fb[ks]  = *(const short8*)(bufB + br * 128 + co);             \
            }                                                                 \
            asm volatile("s_waitcnt lgkmcnt(0)" ::: "memory");                \
            __builtin_amdgcn_sched_barrier(0);                                \
            __builtin_amdgcn_s_setprio(1);                                    \
            _Pragma("unroll")                                                 \
            for (int ks = 0; ks < 4; ++ks) {                                  \
                acc[m2][nn]     = mfma_bf16(fa0[ks], fb[ks], acc[m2][nn]);    \
                acc[m2 + 1][nn] = mfma_bf16(fa1[ks], fb[ks], acc[m2 + 1][nn]);\
            }                                                                 \
            __builtin_amdgcn_s_setprio(0);                                    \
        }                                                                     \
        asm volatile("s_waitcnt vmcnt(0)" ::: "memory");                      \
        __builtin_amdgcn_s_barrier();                                         \
        bsel ^= 1;                                                            \
    }

// ---------------------------------------------------------------------------
// GEMM1: H[offs[e]+row][f] = relu( xn[tok(row)] . wip[e][half*FH+f] )
// tiles 256M x 256N, K = 768 (12 K-tiles). grid: (mt*6 + nt)*8 + e.
// ---------------------------------------------------------------------------
__global__ __launch_bounds__(512, 2)
void gemm1_kernel(const unsigned short* __restrict__ xn,
                  const unsigned short* __restrict__ wip,
                  const int* __restrict__ counts,
                  const int* __restrict__ lists,
                  unsigned short* __restrict__ H, int half)
{
    __shared__ __align__(16) char smem[131072];   // 2 x (A 32K + B 32K)
    __shared__ int s_tok[256];

    const int bid = blockIdx.x;
    const int e  = bid & 7;
    const int mt = (bid >> 3) / 6;
    const int nt = (bid >> 3) % 6;
    const int cnt = counts[e];
    const int base = mt * 256;
    if (base >= cnt) return;
    int offe = 0;
    for (int i = 0; i < e; ++i) offe += counts[i];

    const int tid = threadIdx.x;
    const int w = tid >> 6, l = tid & 63;
    const int lo = l & 31, hi = l >> 5;
    const int wr = w >> 2;        // M-half 0/1
    const int wcn = w & 3;        // N-quarter 0..3

    if (tid < 256) {
        const int idx = base + tid;
        s_tok[tid] = (idx < cnt) ? (lists[e * T + idx] >> 1) : 0;
    }
    __syncthreads();

    // staging: phase p stages rows p*64 + (tid>>3), swizzled 16B chunk
    const int srow = tid >> 3;                       // 0..63
    const int chS = ((tid & 7) ^ (srow & 7)) * 8;    // chunk in shorts
    const int dOff = srow * 128 + (tid & 7) * 16;    // LDS dest (linear)
    const unsigned short* aS[4];
    const unsigned short* bS[4];
#pragma unroll
    for (int p = 0; p < 4; ++p) {
        const int r = p * 64 + srow;
        aS[p] = xn + (size_t)s_tok[r] * D + chS;
        bS[p] = wip + ((size_t)e * F + half * FH + nt * 256 + r) * D + chS;
    }

    f32x16 acc[4][2];
#pragma unroll
    for (int m = 0; m < 4; ++m)
#pragma unroll
        for (int n = 0; n < 2; ++n)
#pragma unroll
            for (int q = 0; q < 16; ++q) acc[m][n][q] = 0.f;

    const int rx = (lo & 7) << 4;

    GEMM8W_LOOP(12)

    // epilogue: relu -> bf16 -> H (rows >= cnt clamped)
    const int cb = nt * 256 + wcn * 64 + lo;
#pragma unroll
    for (int m = 0; m < 4; ++m) {
#pragma unroll
        for (int r = 0; r < 16; ++r) {
            const int crow = (r & 3) + 8 * (r >> 2) + 4 * hi;
            const int lrow = wr * 128 + m * 32 + crow;
            if (base + lrow < cnt) {
                unsigned short* hp = H + (size_t)(offe + base + lrow) * FH + cb;
                hp[0]  = f2bf(fmaxf(acc[m][0][r], 0.f));
                hp[32] = f2bf(fmaxf(acc[m][1][r], 0.f));
            }
        }
    }
}

// ---------------------------------------------------------------------------
// GEMM2: ff[tok][d] (+)= w_tok * ( H[offs[e]+row] . wop[e][d][half*FH..] )
// tiles 256M x 256N (N=768 -> 3 nt), K = 1536 (24 K-tiles).
// mode 0: atomicAdd into out; mode 1: ffout = ; mode 2: ffout += .
// ---------------------------------------------------------------------------
__global__ __launch_bounds__(512, 2)
void gemm2_kernel(const unsigned short* __restrict__ H,
                  const unsigned short* __restrict__ wop,
                  const int* __restrict__ counts,
                  const int* __restrict__ lists, const float* __restrict__ wlist,
                  float* __restrict__ out, float* __restrict__ ffout,
                  int half, int mode)
{
    __shared__ __align__(16) char smem[131072];
    __shared__ int   s_tok[256];
    __shared__ float s_wgt[256];

    const int bid = blockIdx.x;
    const int e  = bid & 7;
    const int mt = (bid >> 3) / 3;
    const int nt = (bid >> 3) % 3;
    const int cnt = counts[e];
    const int base = mt * 256;
    if (base >= cnt) return;
    int offe = 0;
    for (int i = 0; i < e; ++i) offe += counts[i];

    const int tid = threadIdx.x;
    const int w = tid >> 6, l = tid & 63;
    const int lo = l & 31, hi = l >> 5;
    const int wr = w >> 2;
    const int wcn = w & 3;

    if (tid < 256) {
        const int idx = base + tid;
        const bool v = idx < cnt;
        s_tok[tid] = v ? lists[e * T + idx] : 0;
        s_wgt[tid] = v ? wlist[e * T + idx] : 0.f;
    }
    __syncthreads();

    const int srow = tid >> 3;
    const int chS = ((tid & 7) ^ (srow & 7)) * 8;
    const int dOff = srow * 128 + (tid & 7) * 16;
    const unsigned short* aS[4];
    const unsigned short* bS[4];
#pragma unroll
    for (int p = 0; p < 4; ++p) {
        const int r = p * 64 + srow;
        aS[p] = H + (size_t)(offe + base + r) * FH + chS;
        bS[p] = wop + ((size_t)e * D + nt * 256 + r) * F + half * FH + chS;
    }

    f32x16 acc[4][2];
#pragma unroll
    for (int m = 0; m < 4; ++m)
#pragma unroll
        for (int n = 0; n < 2; ++n)
#pragma unroll
            for (int q = 0; q < 16; ++q) acc[m][n][q] = 0.f;

    const int rx = (lo & 7) << 4;

    GEMM8W_LOOP(24)

    const int cb = nt * 256 + wcn * 64 + lo;
#pragma unroll
    for (int m = 0; m < 4; ++m) {
#pragma unroll
        for (int r = 0; r < 16; ++r) {
            const int crow = (r & 3) + 8 * (r >> 2) + 4 * hi;
            const int lrow = wr * 128 + m * 32 + crow;
            if (base + lrow < cnt) {
                const int pk = s_tok[lrow];
                const float wgt = s_wgt[lrow];
                const float v0 = wgt * acc[m][0][r];
                const float v1 = wgt * acc[m][1][r];
                if (mode == 0) {
                    float* dst = out + (size_t)(pk >> 1) * D + cb;
                    atomicAdd(dst,      v0);
                    atomicAdd(dst + 32, v1);
                } else {
                    float* dst = ffout + ((size_t)(pk & 1) * T + (pk >> 1)) * D + cb;
                    if (mode == 1) { dst[0] = v0;  dst[32] = v1; }
                    else           { dst[0] += v0; dst[32] += v1; }
                }
            }
        }
    }
}

// ---------------------------------------------------------------------------
// Combine (ffout mode only): out (= wsum*x) += ffout[0] + ffout[1]
// ---------------------------------------------------------------------------
__global__ __launch_bounds__(256)
void combine_kernel(const float* __restrict__ ffout, float* __restrict__ out)
{
    const long long i4 = ((long long)blockIdx.x * 256 + threadIdx.x) * 4;
    float4 o  = *(const float4*)(out + i4);
    float4 f0 = *(const float4*)(ffout + i4);
    float4 f1 = *(const float4*)(ffout + (long long)T * D + i4);
    o.x += f0.x + f1.x; o.y += f0.y + f1.y;
    o.z += f0.z + f1.z; o.w += f0.w + f1.w;
    *(float4*)(out + i4) = o;
}

// ---------------------------------------------------------------------------
extern "C" void kernel_launch(void* const* d_in, const int* in_sizes, int n_in,
                              void* d_out, int out_size, void* d_ws, size_t ws_size,
                              hipStream_t stream) {
    const float* x   = (const float*)d_in[0];   // [T, D]
    const float* rw  = (const float*)d_in[1];   // [E, D]
    const float* lnw = (const float*)d_in[2];   // [E, D]
    const float* wi  = (const float*)d_in[3];   // [E, F, D]
    const float* wo  = (const float*)d_in[4];   // [E, D, F]

    float* out    = (float*)d_out;                    // [T, D]
    float* logits = (float*)d_out + (size_t)T * D;    // [T, E]

    char* ws = (char*)d_ws;
    int*            counts = (int*)(ws);                       // 64 B
    int*            sel    = (int*)(ws + 4096);                // 32 KB
    float2*         w01    = (float2*)(ws + 65536);            // 64 KB
    int*            lists  = (int*)(ws + 131072);              // 256 KB
    float*          wlist  = (float*)(ws + 393216);            // 256 KB
    unsigned short* xn     = (unsigned short*)(ws + 1048576);  // 12.6 MB
    unsigned short* wip    = (unsigned short*)(ws + 13631488); // 37.7 MB
    unsigned short* wop    = (unsigned short*)(ws + 51380224); // 37.7 MB
    unsigned short* H      = (unsigned short*)(ws + 89128960); // 51.1 MB (ends 140247040)
    float*          ffout  = (float*)(ws + 140247040);         // 50.3 MB (optional)

    // ffout path needs 190.6 MB of ws; ws_size is fixed per deployment, so
    // this branch is deterministic across calls.
    const bool big = ws_size >= 190578688ULL;

    convert_weights<<<36864, 256, 0, stream>>>(wi, wo, lnw, wip, wop);

    router_norm_kernel<<<T / 4, 256, 0, stream>>>(x, rw, logits, xn, out,
                                                  sel, w01);

    build_lists<<<E, 256, 0, stream>>>(sel, w01, counts, lists, wlist);

    for (int h = 0; h < 2; ++h) {
        // worst-case grids (cap 8192 rows/expert = 32 mt); early-exit past cnt
        gemm1_kernel<<<32 * 6 * 8, 512, 0, stream>>>(xn, wip, counts,
                                                     lists, H, h);
        const int mode = big ? (h ? 2 : 1) : 0;
        gemm2_kernel<<<32 * 3 * 8, 512, 0, stream>>>(H, wop, counts,
                                                     lists, wlist, out,
                                                     ffout, h, mode);
    }

    if (big) combine_kernel<<<T * D / 4 / 256, 256, 0, stream>>>(ffout, out);
}

// Round 9
// 362.265 us; speedup vs baseline: 1.2644x; 1.2644x over previous
//
#include <hip/hip_runtime.h>
#include <hip/hip_bf16.h>
#include <math.h>

typedef short short8 __attribute__((ext_vector_type(8)));
typedef float f32x16 __attribute__((ext_vector_type(16)));

constexpr int D = 768;    // model dim
constexpr int E = 8;      // experts
constexpr int F = 3072;   // ffn dim
constexpr int T = 8192;   // tokens
constexpr float EPS = 1e-6f;

static __device__ inline unsigned short f2bf(float f) {
    __hip_bfloat16 h = __float2bfloat16(f);
    return *reinterpret_cast<unsigned short*>(&h);
}

static __device__ inline f32x16 mfma_bf16(short8 a, short8 b, f32x16 c) {
    return __builtin_amdgcn_mfma_f32_32x32x16_bf16(a, b, c, 0, 0, 0);
}

// async global->LDS, 16B per lane; LDS dest = wave-uniform base + lane*16
#define GLL16(g, s) __builtin_amdgcn_global_load_lds( \
    (const __attribute__((address_space(1))) unsigned int*)(g), \
    (__attribute__((address_space(3))) unsigned int*)(s), 16, 0, 0)

// ---------------------------------------------------------------------------
// Weight conversion: wi' = bf16(wi * ln_w) (ln_w folded), wo' = bf16(wo).
// ---------------------------------------------------------------------------
__global__ __launch_bounds__(256)
void convert_weights(const float* __restrict__ wi, const float* __restrict__ wo,
                     const float* __restrict__ lnw,
                     unsigned short* __restrict__ wip, unsigned short* __restrict__ wop)
{
    const unsigned NWI = (unsigned)E * F * D;
    unsigned i4 = (blockIdx.x * 256u + threadIdx.x) * 4u;
    if (i4 < NWI) {
        float4 v = *(const float4*)(wi + i4);
        unsigned e = i4 / (unsigned)(F * D);
        unsigned d = i4 % (unsigned)D;
        float4 l = *(const float4*)(lnw + e * D + d);
        ushort4 o = { f2bf(v.x * l.x), f2bf(v.y * l.y), f2bf(v.z * l.z), f2bf(v.w * l.w) };
        *(ushort4*)(wip + i4) = o;
    } else {
        unsigned j = i4 - NWI;
        float4 v = *(const float4*)(wo + j);
        ushort4 o = { f2bf(v.x), f2bf(v.y), f2bf(v.z), f2bf(v.w) };
        *(ushort4*)(wop + j) = o;
    }
}

// ---------------------------------------------------------------------------
// Router + RMS-norm: logits (exact fp32), top-2, xn = bf16(x*rstd),
// out = wsum*x (residual term), per-token meta (sel, w01). NO atomics.
// ---------------------------------------------------------------------------
__global__ __launch_bounds__(256)
void router_norm_kernel(const float* __restrict__ x,
                        const float* __restrict__ rw,
                        float* __restrict__ logits,        // [T, E]
                        unsigned short* __restrict__ xn,   // [T, D] bf16
                        float* __restrict__ out,           // [T, D] <- wsum*x
                        int*   __restrict__ sel,           // [T] e0 | e1<<4
                        float2* __restrict__ w01)          // [T] (w0, w1)
{
    const int lane = threadIdx.x & 63;
    const int wid  = threadIdx.x >> 6;
    const int t = blockIdx.x * 4 + wid;
    if (t >= T) return;

    const float* xr = x + (size_t)t * D;
    float xv[12];
    float acc[8];
#pragma unroll
    for (int e = 0; e < 8; ++e) acc[e] = 0.f;
    float ssq = 0.f;
#pragma unroll
    for (int i = 0; i < 12; ++i) {
        const int k = lane + 64 * i;
        const float v = xr[k];
        xv[i] = v;
        ssq += v * v;
#pragma unroll
        for (int e = 0; e < 8; ++e) acc[e] += v * rw[e * D + k];
    }
#pragma unroll
    for (int off = 32; off; off >>= 1) {
        ssq += __shfl_xor(ssq, off);
#pragma unroll
        for (int e = 0; e < 8; ++e) acc[e] += __shfl_xor(acc[e], off);
    }

    int e0 = 0; float m0 = acc[0];
#pragma unroll
    for (int e = 1; e < 8; ++e) if (acc[e] > m0) { m0 = acc[e]; e0 = e; }
    int e1 = -1; float m1 = -3.4e38f;
#pragma unroll
    for (int e = 0; e < 8; ++e) if (e != e0 && acc[e] > m1) { m1 = acc[e]; e1 = e; }

    const float r  = expf(m1 - m0);
    const float w0 = 1.f / (1.f + r);
    const float w1 = r * w0;
    const float wsum = w0 + w1;
    const float rs = rsqrtf(ssq * (1.f / (float)D) + EPS);

    if (lane == 0) {
#pragma unroll
        for (int e = 0; e < 8; ++e) logits[t * 8 + e] = acc[e];
        sel[t] = e0 | (e1 << 4);
        w01[t] = make_float2(w0, w1);
    }

#pragma unroll
    for (int i = 0; i < 12; ++i) {
        const int k = lane + 64 * i;
        xn[(size_t)t * D + k] = f2bf(xv[i] * rs);
        out[(size_t)t * D + k] = wsum * xv[i];
    }
}

// ---------------------------------------------------------------------------
// Expert-list build, 3 tiny kernels, zero atomics, deterministic.
// ---------------------------------------------------------------------------
__global__ __launch_bounds__(256)
void count_kernel(const int* __restrict__ sel, int* __restrict__ counts)
{
    const int e = blockIdx.x;
    const int tid = threadIdx.x;
    int c = 0;
    for (int t = tid; t < T; t += 256) {
        const int s = sel[t];
        c += ((s & 15) == e) + (((s >> 4) & 15) == e);
    }
#pragma unroll
    for (int off = 32; off; off >>= 1) c += __shfl_xor(c, off);
    __shared__ int ws4[4];
    if ((tid & 63) == 0) ws4[tid >> 6] = c;
    __syncthreads();
    if (tid == 0) counts[e] = ws4[0] + ws4[1] + ws4[2] + ws4[3];
}

__global__ void prefix_kernel(const int* __restrict__ counts, int* __restrict__ offs)
{
    if (threadIdx.x == 0 && blockIdx.x == 0) {
        int a = 0;
#pragma unroll
        for (int e = 0; e < 8; ++e) { offs[e] = a; a += counts[e]; }
        offs[8] = a;
    }
}

__global__ __launch_bounds__(256)
void place_kernel(const int* __restrict__ sel, const float2* __restrict__ w01,
                  const int* __restrict__ offs,
                  int* __restrict__ lists, float* __restrict__ wlist)
{
    const int e = blockIdx.x;
    const int base = offs[e];
    const int tid = threadIdx.x;
    const int lane = tid & 63;
    const int wv = tid >> 6;
    __shared__ int wtot[4];
    int cnt = 0;
    for (int c0 = 0; c0 < T; c0 += 256) {
        const int t = c0 + tid;
        const int s = sel[t];
        const bool m1 = ((s >> 4) & 15) == e;
        const bool m = ((s & 15) == e) || m1;
        const unsigned long long b = __ballot(m);
        const int pre = __popcll(b & ((1ULL << lane) - 1ULL));
        if (lane == 0) wtot[wv] = __popcll(b);
        __syncthreads();
        int wbase = 0;
#pragma unroll
        for (int i = 0; i < 4; ++i) if (i < wv) wbase += wtot[i];
        if (m) {
            const int pos = base + cnt + wbase + pre;
            lists[pos] = (t << 1) | (m1 ? 1 : 0);
            const float2 w = w01[t];
            wlist[pos] = m1 ? w.y : w.x;
        }
        cnt += wtot[0] + wtot[1] + wtot[2] + wtot[3];
        __syncthreads();
    }
}

// ===========================================================================
// 256x256 8-wave 2-phase-minimum GEMM core (guide T3 short form).
// BK=64, dbuf 128 KB LDS, 512 thr; wave grid 2M x 4N -> wave tile 128x64.
// Per K-tile: STAGE(kt+1) FIRST (8 GLL16, ~550cyc cover) -> two sub-phases
// {12 dedup'd ds_read_b128 -> lgkmcnt(0)+schedbar -> setprio(1) 16 MFMA
// setprio(0)} -> vmcnt(0) -> s_barrier. 0.75 ds_reads/MFMA.
// Rule-21 swizzle: linear LDS dest + inverse-swizzled global src + swz read.
// ===========================================================================

#define STAGE8(kOff, nb)                                                      \
    _Pragma("unroll")                                                         \
    for (int p = 0; p < 4; ++p) {                                             \
        GLL16(aS[p] + (kOff), (nb) + p * 8192 + dOff);                        \
        GLL16(bS[p] + (kOff), (nb) + 32768 + p * 8192 + dOff);                \
    }

#define GEMM2PH_LOOP(NKT)                                                     \
    STAGE8(0, smem)                                                           \
    asm volatile("s_waitcnt vmcnt(0)" ::: "memory");                          \
    __syncthreads();                                                          \
    int cur = 0;                                                              \
    for (int kt = 0; kt < (NKT); ++kt) {                                      \
        char* nb = smem + ((cur ^ 1) * 65536);                                \
        if (kt + 1 < (NKT)) { STAGE8((kt + 1) * 64, nb) }                     \
        const char* bufA = smem + cur * 65536;                                \
        const char* bufB = bufA + 32768;                                      \
        _Pragma("unroll")                                                     \
        for (int s = 0; s < 2; ++s) {                                         \
            short8 fa[4][2], fb[2][2];                                        \
            _Pragma("unroll")                                                 \
            for (int k2 = 0; k2 < 2; ++k2) {                                  \
                const int ks = s * 2 + k2;                                    \
                const int co = (hi * 16 + ks * 32) ^ rx;                      \
                _Pragma("unroll")                                             \
                for (int m = 0; m < 4; ++m)                                   \
                    fa[m][k2] = *(const short8*)(bufA +                       \
                        (wr * 128 + m * 32 + lo) * 128 + co);                 \
                _Pragma("unroll")                                             \
                for (int n = 0; n < 2; ++n)                                   \
                    fb[n][k2] = *(const short8*)(bufB +                       \
                        (wcn * 64 + n * 32 + lo) * 128 + co);                 \
            }                                                                 \
            asm volatile("s_waitcnt lgkmcnt(0)" ::: "memory");                \
            __builtin_amdgcn_sched_barrier(0);                                \
            __builtin_amdgcn_s_setprio(1);                                    \
            _Pragma("unroll")                                                 \
            for (int k2 = 0; k2 < 2; ++k2)                                    \
                _Pragma("unroll")                                             \
                for (int m = 0; m < 4; ++m) {                                 \
                    acc[m][0] = mfma_bf16(fa[m][k2], fb[0][k2], acc[m][0]);   \
                    acc[m][1] = mfma_bf16(fa[m][k2], fb[1][k2], acc[m][1]);   \
                }                                                             \
            __builtin_amdgcn_s_setprio(0);                                    \
        }                                                                     \
        asm volatile("s_waitcnt vmcnt(0)" ::: "memory");                      \
        __builtin_amdgcn_s_barrier();                                         \
        cur ^= 1;                                                             \
    }

// ---------------------------------------------------------------------------
// GEMM1: H[offs[e]+row][f] = relu( xn[tok(row)] . wip[e][f] ), full F=3072.
// grid: ((mt*12 + nt) << 3) | e ; active blocks exit past cnt.
// ---------------------------------------------------------------------------
__global__ __launch_bounds__(512, 2)
void gemm1_kernel(const unsigned short* __restrict__ xn,
                  const unsigned short* __restrict__ wip,
                  const int* __restrict__ offs,
                  const int* __restrict__ lists,
                  unsigned short* __restrict__ H)
{
    __shared__ __align__(16) char smem[131072];   // 2 x (A 32K + B 32K)
    __shared__ int s_tok[256];

    const int bid = blockIdx.x;
    const int e  = bid & 7;
    const int q  = bid >> 3;
    const int mt = q / 12;
    const int nt = q % 12;
    const int offe = offs[e];
    const int cnt = offs[e + 1] - offe;
    const int base = mt * 256;
    if (base >= cnt) return;

    const int tid = threadIdx.x;
    const int w = tid >> 6, l = tid & 63;
    const int lo = l & 31, hi = l >> 5;
    const int wr = w >> 2;        // M-half 0/1
    const int wcn = w & 3;        // N-quarter 0..3

    if (tid < 256) {
        const int idx = base + tid;
        s_tok[tid] = (idx < cnt) ? (lists[offe + idx] >> 1) : 0;
    }
    __syncthreads();

    // staging: thread covers rows p*64 + (tid>>3), inverse-swizzled 16B chunk
    const int srow = tid >> 3;                       // 0..63
    const int chS = ((tid & 7) ^ (srow & 7)) * 8;    // chunk in shorts
    const int dOff = srow * 128 + (tid & 7) * 16;    // linear LDS dest
    const unsigned short* aS[4];
    const unsigned short* bS[4];
#pragma unroll
    for (int p = 0; p < 4; ++p) {
        const int r = p * 64 + srow;
        aS[p] = xn + (size_t)s_tok[r] * D + chS;
        bS[p] = wip + ((size_t)e * F + nt * 256 + r) * D + chS;
    }

    f32x16 acc[4][2];
#pragma unroll
    for (int m = 0; m < 4; ++m)
#pragma unroll
        for (int n = 0; n < 2; ++n)
#pragma unroll
            for (int qq = 0; qq < 16; ++qq) acc[m][n][qq] = 0.f;

    const int rx = (lo & 7) << 4;

    GEMM2PH_LOOP(12)   // K = 768

    // epilogue: relu -> bf16 -> H (rows >= cnt clamped)
    const int cb = nt * 256 + wcn * 64 + lo;
#pragma unroll
    for (int m = 0; m < 4; ++m) {
#pragma unroll
        for (int r = 0; r < 16; ++r) {
            const int crow = (r & 3) + 8 * (r >> 2) + 4 * hi;
            const int lrow = wr * 128 + m * 32 + crow;
            if (base + lrow < cnt) {
                unsigned short* hp = H + (size_t)(offe + base + lrow) * F + cb;
                hp[0]  = f2bf(fmaxf(acc[m][0][r], 0.f));
                hp[32] = f2bf(fmaxf(acc[m][1][r], 0.f));
            }
        }
    }
}

// ---------------------------------------------------------------------------
// GEMM2: out[tok][d] += w_tok * ( H[offs[e]+row][kh-half] . wop[e][d][kh] )
// kh in {0,1} splits K=3072 into 1536-halves -> 4 atomic adds per element
// (2 slots x 2 kh; scattered addresses, no convoy).
// grid: ((kh*96 + mt*3 + nt) << 3) | e
// ---------------------------------------------------------------------------
__global__ __launch_bounds__(512, 2)
void gemm2_kernel(const unsigned short* __restrict__ H,
                  const unsigned short* __restrict__ wop,
                  const int* __restrict__ offs,
                  const int* __restrict__ lists, const float* __restrict__ wlist,
                  float* __restrict__ out)
{
    __shared__ __align__(16) char smem[131072];
    __shared__ int   s_tok[256];
    __shared__ float s_wgt[256];

    const int bid = blockIdx.x;
    const int e  = bid & 7;
    const int q  = bid >> 3;
    const int kh = q / 96;
    const int rm = q % 96;
    const int mt = rm / 3;
    const int nt = rm % 3;
    const int offe = offs[e];
    const int cnt = offs[e + 1] - offe;
    const int base = mt * 256;
    if (base >= cnt) return;

    const int tid = threadIdx.x;
    const int w = tid >> 6, l = tid & 63;
    const int lo = l & 31, hi = l >> 5;
    const int wr = w >> 2;
    const int wcn = w & 3;

    if (tid < 256) {
        const int idx = base + tid;
        const bool v = idx < cnt;
        s_tok[tid] = v ? lists[offe + idx] : 0;
        s_wgt[tid] = v ? wlist[offe + idx] : 0.f;
    }
    __syncthreads();

    const int srow = tid >> 3;
    const int chS = ((tid & 7) ^ (srow & 7)) * 8;
    const int dOff = srow * 128 + (tid & 7) * 16;
    const unsigned short* aS[4];
    const unsigned short* bS[4];
#pragma unroll
    for (int p = 0; p < 4; ++p) {
        const int r = p * 64 + srow;
        aS[p] = H + (size_t)(offe + base + r) * F + kh * 1536 + chS;
        bS[p] = wop + ((size_t)e * D + nt * 256 + r) * F + kh * 1536 + chS;
    }

    f32x16 acc[4][2];
#pragma unroll
    for (int m = 0; m < 4; ++m)
#pragma unroll
        for (int n = 0; n < 2; ++n)
#pragma unroll
            for (int qq = 0; qq < 16; ++qq) acc[m][n][qq] = 0.f;

    const int rx = (lo & 7) << 4;

    GEMM2PH_LOOP(24)   // K = 1536 per kh-half

    const int cb = nt * 256 + wcn * 64 + lo;
#pragma unroll
    for (int m = 0; m < 4; ++m) {
#pragma unroll
        for (int r = 0; r < 16; ++r) {
            const int crow = (r & 3) + 8 * (r >> 2) + 4 * hi;
            const int lrow = wr * 128 + m * 32 + crow;
            if (base + lrow < cnt) {
                const int tk = s_tok[lrow] >> 1;
                const float wgt = s_wgt[lrow];
                float* dst = out + (size_t)tk * D + cb;
                atomicAdd(dst,      wgt * acc[m][0][r]);
                atomicAdd(dst + 32, wgt * acc[m][1][r]);
            }
        }
    }
}

// ---------------------------------------------------------------------------
extern "C" void kernel_launch(void* const* d_in, const int* in_sizes, int n_in,
                              void* d_out, int out_size, void* d_ws, size_t ws_size,
                              hipStream_t stream) {
    const float* x   = (const float*)d_in[0];   // [T, D]
    const float* rw  = (const float*)d_in[1];   // [E, D]
    const float* lnw = (const float*)d_in[2];   // [E, D]
    const float* wi  = (const float*)d_in[3];   // [E, F, D]
    const float* wo  = (const float*)d_in[4];   // [E, D, F]

    float* out    = (float*)d_out;                    // [T, D]
    float* logits = (float*)d_out + (size_t)T * D;    // [T, E]

    // ws layout (190,546,048 B total; proven ws_size >= 190,578,688)
    char* ws = (char*)d_ws;
    unsigned short* xn     = (unsigned short*)(ws);               // 12.58 MB
    unsigned short* wip    = (unsigned short*)(ws + 12582912);    // 37.75 MB
    unsigned short* wop    = (unsigned short*)(ws + 50331648);    // 37.75 MB
    unsigned short* H      = (unsigned short*)(ws + 88080384);    // 16640 x 3072 bf16 = 102.24 MB
    int*            counts = (int*)(ws + 190316544);              // 64 B
    int*            offs   = (int*)(ws + 190316608);              // 64 B (9 ints)
    int*            sel    = (int*)(ws + 190316672);              // 32 KB
    float2*         w01    = (float2*)(ws + 190349440);           // 64 KB
    int*            lists  = (int*)(ws + 190414976);              // 64 KB (2T packed)
    float*          wlist  = (float*)(ws + 190480512);            // 64 KB

    convert_weights<<<36864, 256, 0, stream>>>(wi, wo, lnw, wip, wop);

    router_norm_kernel<<<T / 4, 256, 0, stream>>>(x, rw, logits, xn, out,
                                                  sel, w01);

    count_kernel<<<E, 256, 0, stream>>>(sel, counts);
    prefix_kernel<<<1, 1, 0, stream>>>(counts, offs);
    place_kernel<<<E, 256, 0, stream>>>(sel, w01, offs, lists, wlist);

    // worst-case grids (cap 8192 rows/expert = 32 mt); blocks exit past cnt
    gemm1_kernel<<<32 * 12 * 8, 512, 0, stream>>>(xn, wip, offs, lists, H);
    gemm2_kernel<<<2 * 32 * 3 * 8, 512, 0, stream>>>(H, wop, offs, lists,
                                                     wlist, out);
}

// Round 10
// 332.102 us; speedup vs baseline: 1.3792x; 1.0908x over previous
//
#include <hip/hip_runtime.h>
#include <hip/hip_bf16.h>
#include <math.h>

typedef short short8 __attribute__((ext_vector_type(8)));
typedef float f32x16 __attribute__((ext_vector_type(16)));

constexpr int D = 768;    // model dim
constexpr int E = 8;      // experts
constexpr int F = 3072;   // ffn dim
constexpr int T = 8192;   // tokens
constexpr float EPS = 1e-6f;

static __device__ inline unsigned short f2bf(float f) {
    __hip_bfloat16 h = __float2bfloat16(f);
    return *reinterpret_cast<unsigned short*>(&h);
}

static __device__ inline f32x16 mfma_bf16(short8 a, short8 b, f32x16 c) {
    return __builtin_amdgcn_mfma_f32_32x32x16_bf16(a, b, c, 0, 0, 0);
}

// async global->LDS, 16B per lane; LDS dest = wave-uniform base + lane*16
#define GLL16(g, s) __builtin_amdgcn_global_load_lds( \
    (const __attribute__((address_space(1))) unsigned int*)(g), \
    (__attribute__((address_space(3))) unsigned int*)(s), 16, 0, 0)

// ---------------------------------------------------------------------------
// Weight conversion: wi' = bf16(wi * ln_w) (ln_w folded), wo' = bf16(wo).
// ---------------------------------------------------------------------------
__global__ __launch_bounds__(256)
void convert_weights(const float* __restrict__ wi, const float* __restrict__ wo,
                     const float* __restrict__ lnw,
                     unsigned short* __restrict__ wip, unsigned short* __restrict__ wop)
{
    const unsigned NWI = (unsigned)E * F * D;
    unsigned i4 = (blockIdx.x * 256u + threadIdx.x) * 4u;
    if (i4 < NWI) {
        float4 v = *(const float4*)(wi + i4);
        unsigned e = i4 / (unsigned)(F * D);
        unsigned d = i4 % (unsigned)D;
        float4 l = *(const float4*)(lnw + e * D + d);
        ushort4 o = { f2bf(v.x * l.x), f2bf(v.y * l.y), f2bf(v.z * l.z), f2bf(v.w * l.w) };
        *(ushort4*)(wip + i4) = o;
    } else {
        unsigned j = i4 - NWI;
        float4 v = *(const float4*)(wo + j);
        ushort4 o = { f2bf(v.x), f2bf(v.y), f2bf(v.z), f2bf(v.w) };
        *(ushort4*)(wop + j) = o;
    }
}

// ---------------------------------------------------------------------------
// Router + RMS-norm: logits (exact fp32), top-2, xn = bf16(x*rstd),
// out = wsum*x (residual term), per-token meta (sel, w01). NO atomics.
// ---------------------------------------------------------------------------
__global__ __launch_bounds__(256)
void router_norm_kernel(const float* __restrict__ x,
                        const float* __restrict__ rw,
                        float* __restrict__ logits,        // [T, E]
                        unsigned short* __restrict__ xn,   // [T, D] bf16
                        float* __restrict__ out,           // [T, D] <- wsum*x
                        int*   __restrict__ sel,           // [T] e0 | e1<<4
                        float2* __restrict__ w01)          // [T] (w0, w1)
{
    const int lane = threadIdx.x & 63;
    const int wid  = threadIdx.x >> 6;
    const int t = blockIdx.x * 4 + wid;
    if (t >= T) return;

    const float* xr = x + (size_t)t * D;
    float xv[12];
    float acc[8];
#pragma unroll
    for (int e = 0; e < 8; ++e) acc[e] = 0.f;
    float ssq = 0.f;
#pragma unroll
    for (int i = 0; i < 12; ++i) {
        const int k = lane + 64 * i;
        const float v = xr[k];
        xv[i] = v;
        ssq += v * v;
#pragma unroll
        for (int e = 0; e < 8; ++e) acc[e] += v * rw[e * D + k];
    }
#pragma unroll
    for (int off = 32; off; off >>= 1) {
        ssq += __shfl_xor(ssq, off);
#pragma unroll
        for (int e = 0; e < 8; ++e) acc[e] += __shfl_xor(acc[e], off);
    }

    int e0 = 0; float m0 = acc[0];
#pragma unroll
    for (int e = 1; e < 8; ++e) if (acc[e] > m0) { m0 = acc[e]; e0 = e; }
    int e1 = -1; float m1 = -3.4e38f;
#pragma unroll
    for (int e = 0; e < 8; ++e) if (e != e0 && acc[e] > m1) { m1 = acc[e]; e1 = e; }

    const float r  = expf(m1 - m0);
    const float w0 = 1.f / (1.f + r);
    const float w1 = r * w0;
    const float wsum = w0 + w1;
    const float rs = rsqrtf(ssq * (1.f / (float)D) + EPS);

    if (lane == 0) {
#pragma unroll
        for (int e = 0; e < 8; ++e) logits[t * 8 + e] = acc[e];
        sel[t] = e0 | (e1 << 4);
        w01[t] = make_float2(w0, w1);
    }

#pragma unroll
    for (int i = 0; i < 12; ++i) {
        const int k = lane + 64 * i;
        xn[(size_t)t * D + k] = f2bf(xv[i] * rs);
        out[(size_t)t * D + k] = wsum * xv[i];
    }
}

// ---------------------------------------------------------------------------
// Expert-list build, 3 tiny kernels, zero atomics, deterministic.
// ---------------------------------------------------------------------------
__global__ __launch_bounds__(256)
void count_kernel(const int* __restrict__ sel, int* __restrict__ counts)
{
    const int e = blockIdx.x;
    const int tid = threadIdx.x;
    int c = 0;
    for (int t = tid; t < T; t += 256) {
        const int s = sel[t];
        c += ((s & 15) == e) + (((s >> 4) & 15) == e);
    }
#pragma unroll
    for (int off = 32; off; off >>= 1) c += __shfl_xor(c, off);
    __shared__ int ws4[4];
    if ((tid & 63) == 0) ws4[tid >> 6] = c;
    __syncthreads();
    if (tid == 0) counts[e] = ws4[0] + ws4[1] + ws4[2] + ws4[3];
}

__global__ void prefix_kernel(const int* __restrict__ counts, int* __restrict__ offs)
{
    if (threadIdx.x == 0 && blockIdx.x == 0) {
        int a = 0;
#pragma unroll
        for (int e = 0; e < 8; ++e) { offs[e] = a; a += counts[e]; }
        offs[8] = a;
    }
}

__global__ __launch_bounds__(256)
void place_kernel(const int* __restrict__ sel, const float2* __restrict__ w01,
                  const int* __restrict__ offs,
                  int* __restrict__ lists, float* __restrict__ wlist)
{
    const int e = blockIdx.x;
    const int base = offs[e];
    const int tid = threadIdx.x;
    const int lane = tid & 63;
    const int wv = tid >> 6;
    __shared__ int wtot[4];
    int cnt = 0;
    for (int c0 = 0; c0 < T; c0 += 256) {
        const int t = c0 + tid;
        const int s = sel[t];
        const bool m1 = ((s >> 4) & 15) == e;
        const bool m = ((s & 15) == e) || m1;
        const unsigned long long b = __ballot(m);
        const int pre = __popcll(b & ((1ULL << lane) - 1ULL));
        if (lane == 0) wtot[wv] = __popcll(b);
        __syncthreads();
        int wbase = 0;
#pragma unroll
        for (int i = 0; i < 4; ++i) if (i < wv) wbase += wtot[i];
        if (m) {
            const int pos = base + cnt + wbase + pre;
            lists[pos] = (t << 1) | (m1 ? 1 : 0);
            const float2 w = w01[t];
            wlist[pos] = m1 ? w.y : w.x;
        }
        cnt += wtot[0] + wtot[1] + wtot[2] + wtot[3];
        __syncthreads();
    }
}

// ===========================================================================
// Single-buffer 128x128 GEMM core (r6-proven, best per-block rate measured):
// BK=64, 4 waves, 33 KB LDS -> 4 blocks/CU resident; cross-block TLP hides
// the stage drain (m114). Rule-21 swizzle: linear LDS dest + inverse-swizzled
// global src + swizzled ds_read.
// ===========================================================================

// ---------------------------------------------------------------------------
// GEMM1: H[offs[e]+row][f] = relu( xn[tok(row)] . wip[e][f] ), full F.
// grid: ((mt*24 + nt) << 3) | e, mt < 64 (worst-case imbalance safe).
// ---------------------------------------------------------------------------
__global__ __launch_bounds__(256)
void gemm1_kernel(const unsigned short* __restrict__ xn,
                  const unsigned short* __restrict__ wip,
                  const int* __restrict__ offs,
                  const int* __restrict__ lists,
                  unsigned short* __restrict__ H)
{
    __shared__ unsigned short sA[128 * 64];
    __shared__ unsigned short sB[128 * 64];
    __shared__ int s_tok[128];

    const int bid = blockIdx.x;
    const int e  = bid & 7;
    const int q  = bid >> 3;
    const int mt = q / 24;
    const int nt = q % 24;
    const int offe = offs[e];
    const int cnt = offs[e + 1] - offe;
    const int base = mt * 128;
    if (base >= cnt) return;

    const int tid = threadIdx.x;
    const int w = tid >> 6, l = tid & 63;
    const int lo = l & 31, hi = l >> 5;
    const int wr = w >> 1, wc = w & 1;

    if (tid < 128) {
        const int idx = base + tid;
        s_tok[tid] = (idx < cnt) ? (lists[offe + idx] >> 1) : 0;
    }
    __syncthreads();

    // inverse-swizzled global source chunk (16B units within each 128B span)
    const int r = (w * 4 + 0) * 8 + (l >> 3);          // row staged by j=0
    const int chS = ((l & 7) ^ ((l >> 3) & 7)) * 8;    // swizzled chunk, shorts
    const unsigned short* aSrc[4];
    const unsigned short* bSrc[4];
#pragma unroll
    for (int j = 0; j < 4; ++j) {
        const int rj = r + j * 8;
        aSrc[j] = xn + (size_t)s_tok[rj] * D + chS;
        bSrc[j] = wip + ((size_t)e * F + nt * 128 + rj) * D + chS;
    }
    char* sAc = (char*)sA;
    char* sBc = (char*)sB;

    f32x16 acc00, acc01, acc10, acc11;
#pragma unroll
    for (int qq = 0; qq < 16; ++qq) { acc00[qq] = 0.f; acc01[qq] = 0.f; acc10[qq] = 0.f; acc11[qq] = 0.f; }

    const int rx = (lo & 7) << 4;                   // read-side row XOR
    const int arow0 = (wr * 64 + lo) * 128;
    const int arow1 = arow0 + 32 * 128;
    const int brow0 = (wc * 64 + lo) * 128;
    const int brow1 = brow0 + 32 * 128;

    for (int kt = 0; kt < 12; ++kt) {               // K = 768
        const int k0 = kt * 64;
#pragma unroll
        for (int j = 0; j < 4; ++j) {
            GLL16(aSrc[j] + k0, sAc + (w * 4 + j) * 1024);
            GLL16(bSrc[j] + k0, sBc + (w * 4 + j) * 1024);
        }
        __syncthreads();                 // stage complete + rendezvous
#pragma unroll
        for (int ks = 0; ks < 4; ++ks) {
            const int coff = (hi * 16 + ks * 32) ^ rx;
            short8 a0 = *(const short8*)(sAc + arow0 + coff);
            short8 a1 = *(const short8*)(sAc + arow1 + coff);
            short8 b0 = *(const short8*)(sBc + brow0 + coff);
            short8 b1 = *(const short8*)(sBc + brow1 + coff);
            acc00 = mfma_bf16(a0, b0, acc00);
            acc01 = mfma_bf16(a0, b1, acc01);
            acc10 = mfma_bf16(a1, b0, acc10);
            acc11 = mfma_bf16(a1, b1, acc11);
        }
        __syncthreads();                 // all reads done before next stage
    }

    // epilogue: relu -> bf16 -> H (rows >= cnt clamped; packed full-F layout)
    const int cbase = nt * 128 + wc * 64 + lo;
#pragma unroll
    for (int rr = 0; rr < 16; ++rr) {
        const int crow = (rr & 3) + 8 * (rr >> 2) + 4 * hi;
        int lrow = wr * 64 + crow;
        if (base + lrow < cnt) {
            unsigned short* hp = H + (size_t)(offe + base + lrow) * F + cbase;
            hp[0]  = f2bf(fmaxf(acc00[rr], 0.f));
            hp[32] = f2bf(fmaxf(acc01[rr], 0.f));
        }
        lrow += 32;
        if (base + lrow < cnt) {
            unsigned short* hp = H + (size_t)(offe + base + lrow) * F + cbase;
            hp[0]  = f2bf(fmaxf(acc10[rr], 0.f));
            hp[32] = f2bf(fmaxf(acc11[rr], 0.f));
        }
    }
}

// ---------------------------------------------------------------------------
// GEMM2: out[tok][d] += w_tok * ( H[offs[e]+row][kh half] . wop[e][d][kh] )
// kh in {0,1} splits K=3072 -> doubles active blocks (TLP) ; 4 scattered
// atomic adds per out element (2 slots x 2 kh), no convoy.
// grid: ((kh*384 + mt*6 + nt) << 3) | e, mt < 64.
// ---------------------------------------------------------------------------
__global__ __launch_bounds__(256)
void gemm2_kernel(const unsigned short* __restrict__ H,
                  const unsigned short* __restrict__ wop,
                  const int* __restrict__ offs,
                  const int* __restrict__ lists, const float* __restrict__ wlist,
                  float* __restrict__ out)
{
    __shared__ unsigned short sA[128 * 64];
    __shared__ unsigned short sB[128 * 64];
    __shared__ int   s_tok[128];
    __shared__ float s_wgt[128];

    const int bid = blockIdx.x;
    const int e  = bid & 7;
    const int q  = bid >> 3;
    const int kh = q / 384;
    const int rm = q % 384;
    const int mt = rm / 6;
    const int nt = rm % 6;
    const int offe = offs[e];
    const int cnt = offs[e + 1] - offe;
    const int base = mt * 128;
    if (base >= cnt) return;

    const int tid = threadIdx.x;
    const int w = tid >> 6, l = tid & 63;
    const int lo = l & 31, hi = l >> 5;
    const int wr = w >> 1, wc = w & 1;

    if (tid < 128) {
        const int idx = base + tid;
        const bool v = idx < cnt;
        s_tok[tid] = v ? lists[offe + idx] : 0;
        s_wgt[tid] = v ? wlist[offe + idx] : 0.f;
    }
    __syncthreads();

    const int r = (w * 4 + 0) * 8 + (l >> 3);
    const int chS = ((l & 7) ^ ((l >> 3) & 7)) * 8;
    const unsigned short* aSrc[4];
    const unsigned short* bSrc[4];
#pragma unroll
    for (int j = 0; j < 4; ++j) {
        const int rj = r + j * 8;
        aSrc[j] = H + (size_t)(offe + base + rj) * F + kh * 1536 + chS;
        bSrc[j] = wop + ((size_t)e * D + nt * 128 + rj) * F + kh * 1536 + chS;
    }
    char* sAc = (char*)sA;
    char* sBc = (char*)sB;

    f32x16 acc00, acc01, acc10, acc11;
#pragma unroll
    for (int qq = 0; qq < 16; ++qq) { acc00[qq] = 0.f; acc01[qq] = 0.f; acc10[qq] = 0.f; acc11[qq] = 0.f; }

    const int rx = (lo & 7) << 4;
    const int arow0 = (wr * 64 + lo) * 128;
    const int arow1 = arow0 + 32 * 128;
    const int brow0 = (wc * 64 + lo) * 128;
    const int brow1 = brow0 + 32 * 128;

    for (int kt = 0; kt < 24; ++kt) {               // K = 1536 per kh
        const int k0 = kt * 64;
#pragma unroll
        for (int j = 0; j < 4; ++j) {
            GLL16(aSrc[j] + k0, sAc + (w * 4 + j) * 1024);
            GLL16(bSrc[j] + k0, sBc + (w * 4 + j) * 1024);
        }
        __syncthreads();
#pragma unroll
        for (int ks = 0; ks < 4; ++ks) {
            const int coff = (hi * 16 + ks * 32) ^ rx;
            short8 a0 = *(const short8*)(sAc + arow0 + coff);
            short8 a1 = *(const short8*)(sAc + arow1 + coff);
            short8 b0 = *(const short8*)(sBc + brow0 + coff);
            short8 b1 = *(const short8*)(sBc + brow1 + coff);
            acc00 = mfma_bf16(a0, b0, acc00);
            acc01 = mfma_bf16(a0, b1, acc01);
            acc10 = mfma_bf16(a1, b0, acc10);
            acc11 = mfma_bf16(a1, b1, acc11);
        }
        __syncthreads();
    }

    const int cbase = nt * 128 + wc * 64 + lo;
#pragma unroll
    for (int rr = 0; rr < 16; ++rr) {
        const int crow = (rr & 3) + 8 * (rr >> 2) + 4 * hi;
#pragma unroll
        for (int mh = 0; mh < 2; ++mh) {
            const int lrow = wr * 64 + crow + mh * 32;
            if (base + lrow < cnt) {
                const int tk = s_tok[lrow] >> 1;
                const float wgt = s_wgt[lrow];
                float* dst = out + (size_t)tk * D + cbase;
                atomicAdd(dst,      wgt * (mh ? acc10[rr] : acc00[rr]));
                atomicAdd(dst + 32, wgt * (mh ? acc11[rr] : acc01[rr]));
            }
        }
    }
}

// ---------------------------------------------------------------------------
extern "C" void kernel_launch(void* const* d_in, const int* in_sizes, int n_in,
                              void* d_out, int out_size, void* d_ws, size_t ws_size,
                              hipStream_t stream) {
    const float* x   = (const float*)d_in[0];   // [T, D]
    const float* rw  = (const float*)d_in[1];   // [E, D]
    const float* lnw = (const float*)d_in[2];   // [E, D]
    const float* wi  = (const float*)d_in[3];   // [E, F, D]
    const float* wo  = (const float*)d_in[4];   // [E, D, F]

    float* out    = (float*)d_out;                    // [T, D]
    float* logits = (float*)d_out + (size_t)T * D;    // [T, E]

    // ws layout (190.5 MB total, same proven footprint as r9)
    char* ws = (char*)d_ws;
    unsigned short* xn     = (unsigned short*)(ws);               // 12.58 MB
    unsigned short* wip    = (unsigned short*)(ws + 12582912);    // 37.75 MB
    unsigned short* wop    = (unsigned short*)(ws + 50331648);    // 37.75 MB
    unsigned short* H      = (unsigned short*)(ws + 88080384);    // 16640 x 3072 bf16
    int*            counts = (int*)(ws + 190316544);              // 64 B
    int*            offs   = (int*)(ws + 190316608);              // 64 B (9 ints)
    int*            sel    = (int*)(ws + 190316672);              // 32 KB
    float2*         w01    = (float2*)(ws + 190349440);           // 64 KB
    int*            lists  = (int*)(ws + 190414976);              // 64 KB
    float*          wlist  = (float*)(ws + 190480512);            // 64 KB

    convert_weights<<<36864, 256, 0, stream>>>(wi, wo, lnw, wip, wop);

    router_norm_kernel<<<T / 4, 256, 0, stream>>>(x, rw, logits, xn, out,
                                                  sel, w01);

    count_kernel<<<E, 256, 0, stream>>>(sel, counts);
    prefix_kernel<<<1, 1, 0, stream>>>(counts, offs);
    place_kernel<<<E, 256, 0, stream>>>(sel, w01, offs, lists, wlist);

    // worst-case grids (mt < 64 covers any expert imbalance); dead blocks exit
    gemm1_kernel<<<64 * 24 * 8, 256, 0, stream>>>(xn, wip, offs, lists, H);
    gemm2_kernel<<<2 * 64 * 6 * 8, 256, 0, stream>>>(H, wop, offs, lists,
                                                     wlist, out);
}